// Round 4
// baseline (769.340 us; speedup 1.0000x reference)
//
#include <hip/hip_runtime.h>

typedef _Float16 half8 __attribute__((ext_vector_type(8)));
typedef _Float16 half2t __attribute__((ext_vector_type(2)));
typedef float float4t __attribute__((ext_vector_type(4)));
typedef float float2t __attribute__((ext_vector_type(2)));

#define BATCH 32
#define CIN 64
#define HIN 128
#define WIN 128
#define COUT 128
#define HOUT 126
#define WOUT 126
#define HP 63
#define WP 63
#define NGROUPS 16
#define CPG 8
#define EPSV 1e-5f

#define XS_COLS 66
#define XS_CSTR 72   // cin stride in fp16 elems = 144B: 16B-aligned b128, 8-bank spread

// wT[pos][cout][cin] fp16, pos = kh*3+kw ; also zeroes stats
__global__ __launch_bounds__(256) void wt_kernel(const float* __restrict__ w,
                                                 _Float16* __restrict__ wT,
                                                 float* __restrict__ stats) {
    int idx = blockIdx.x * 256 + threadIdx.x;
    if (idx < BATCH * NGROUPS * 2) stats[idx] = 0.f;
    if (idx >= 9 * COUT * CIN) return;
    int cin = idx & 63;
    int t = idx >> 6;
    int cout = t & 127;
    int pos = t >> 7;
    wT[idx] = (_Float16)w[(cout * CIN + cin) * 9 + pos];
}

// grid: x = oy (126), y = col-half (2), z = batch. 4 waves; wave = 64 couts x 32 px.
__global__ __launch_bounds__(256, 4) void conv_mfma_kernel(
    const float* __restrict__ x, const _Float16* __restrict__ wT,
    const float* __restrict__ bias, float* __restrict__ y,
    float* __restrict__ stats)
{
    __shared__ __align__(16) _Float16 xs[3 * XS_COLS * XS_CSTR];  // 28512 B

    const int tid  = threadIdx.x;
    const int oy   = blockIdx.x;
    const int half = blockIdx.y;
    const int b    = blockIdx.z;

    // ---- stage xs[r][col][cin] = fp16(x[b][cin][oy+r][half*64+col]), col 0..65 ----
    {
        const int cp  = tid & 31;        // cins {2cp, 2cp+1}
        const int seg = tid >> 5;        // 0..7
        const float* xb = x + ((size_t)b * CIN + 2 * cp) * (HIN * WIN) + half * 64;
#pragma unroll
        for (int i = 0; i < 6; i++) {
            int r = i >> 1;
            int col4 = (seg * 2 + (i & 1)) * 4;       // 0..60
            const float* p0 = xb + (size_t)(oy + r) * WIN + col4;
            const float* p1 = p0 + (size_t)HIN * WIN;
            float4t va = *(const float4t*)p0;
            float4t vb = *(const float4t*)p1;
            _Float16* dst = &xs[(r * XS_COLS + col4) * XS_CSTR + 2 * cp];
#pragma unroll
            for (int j = 0; j < 4; j++) {
                half2t hv = { (_Float16)va[j], (_Float16)vb[j] };
                *(half2t*)(dst + j * XS_CSTR) = hv;
            }
        }
        // halo cols 64,65 (zero when out of the input row: half==1 -> x cols 128,129)
        if (tid < 192) {
            int r = tid >> 6;
            int rem = tid & 63;
            int cpz = rem & 31;
            int col = 64 + (rem >> 5);
            int gx = half * 64 + col;
            float v0 = 0.f, v1 = 0.f;
            if (gx < WIN) {
                const float* p = x + ((size_t)b * CIN + 2 * cpz) * (HIN * WIN) + (size_t)(oy + r) * WIN + gx;
                v0 = p[0];
                v1 = p[HIN * WIN];
            }
            half2t hv = { (_Float16)v0, (_Float16)v1 };
            *(half2t*)&xs[(r * XS_COLS + col) * XS_CSTR + 2 * cpz] = hv;
        }
    }
    __syncthreads();

    const int lane = tid & 63;
    const int wv   = tid >> 6;
    const int m    = lane & 15;
    const int q    = lane >> 4;
    const int c0   = (wv >> 1) * 64;     // cout base
    const int px0w = (wv & 1) * 32;      // local pixel base

    float4t acc[4][2];
#pragma unroll
    for (int s = 0; s < 4; s++)
#pragma unroll
        for (int n = 0; n < 2; n++)
            acc[s][n] = (float4t){0.f, 0.f, 0.f, 0.f};

    // A fragments: a[ch][s], prefetch next pos while computing current
    half8 a_cur[2][4], a_nxt[2][4];
    const _Float16* abase = wT + (size_t)(c0 + m) * CIN + q * 8;
#pragma unroll
    for (int ch = 0; ch < 2; ch++)
#pragma unroll
        for (int s = 0; s < 4; s++)
            a_cur[ch][s] = *(const half8*)(abase + ch * 32 + s * 16 * CIN);

#pragma unroll 1
    for (int pos = 0; pos < 9; pos++) {
        const int kh = pos / 3;
        const int kw = pos - kh * 3;

        if (pos < 8) {
            const _Float16* ab = abase + (size_t)(pos + 1) * COUT * CIN;
#pragma unroll
            for (int ch = 0; ch < 2; ch++)
#pragma unroll
                for (int s = 0; s < 4; s++)
                    a_nxt[ch][s] = *(const half8*)(ab + ch * 32 + s * 16 * CIN);
        }

        const _Float16* bb = &xs[(kh * XS_COLS + px0w + m + kw) * XS_CSTR + q * 8];
#pragma unroll
        for (int n = 0; n < 2; n++) {
#pragma unroll
            for (int ch = 0; ch < 2; ch++) {
                half8 bf = *(const half8*)(bb + n * 16 * XS_CSTR + ch * 32);
#pragma unroll
                for (int s = 0; s < 4; s++)
                    acc[s][n] = __builtin_amdgcn_mfma_f32_16x16x32_f16(a_cur[ch][s], bf, acc[s][n], 0, 0, 0);
            }
        }
#pragma unroll
        for (int ch = 0; ch < 2; ch++)
#pragma unroll
            for (int s = 0; s < 4; s++)
                a_cur[ch][s] = a_nxt[ch][s];
    }

    // ---- epilogue: bias, store y (fp32), per-group stats ----
    float sv[4] = {0.f, 0.f, 0.f, 0.f}, ssv[4] = {0.f, 0.f, 0.f, 0.f};
#pragma unroll
    for (int s = 0; s < 4; s++) {
        float bval[4];
#pragma unroll
        for (int reg = 0; reg < 4; reg++)
            bval[reg] = bias[c0 + s * 16 + q * 4 + reg];
#pragma unroll
        for (int n = 0; n < 2; n++) {
            int pix = half * 64 + px0w + n * 16 + m;
            bool valid = pix < WOUT;
            float* yp = y + (((size_t)b * COUT + c0 + s * 16 + q * 4) * HOUT + oy) * WOUT + pix;
#pragma unroll
            for (int reg = 0; reg < 4; reg++) {
                float v = acc[s][n][reg] + bval[reg];
                if (valid) {
                    yp[(size_t)reg * HOUT * WOUT] = v;
                    sv[s] += v;
                    ssv[s] += v * v;
                }
            }
        }
    }
    // lanes 0..31 (q=0,1) -> group c0/8 + s*2; lanes 32..63 -> +1
#pragma unroll
    for (int s = 0; s < 4; s++) {
        float a = sv[s], c = ssv[s];
        for (int off = 16; off; off >>= 1) {
            a += __shfl_down(a, off, 32);
            c += __shfl_down(c, off, 32);
        }
        if ((lane & 31) == 0) {
            int g = (c0 >> 3) + s * 2 + (lane >> 5);
            atomicAdd(&stats[(b * NGROUPS + g) * 2 + 0], a);
            atomicAdd(&stats[(b * NGROUPS + g) * 2 + 1], c);
        }
    }
}

// thread -> (b, c, hp, wp-pair): 2 pooled outputs, float4 loads
__global__ __launch_bounds__(256) void norm_pool_kernel(
    const float* __restrict__ y, const float* __restrict__ stats,
    const float* __restrict__ gnw, const float* __restrict__ gnb,
    const float* __restrict__ scale, float* __restrict__ out)
{
    int idx = blockIdx.x * 256 + threadIdx.x;   // exact: 32*128*63*32 threads
    int wp2 = idx & 31;
    int t = idx >> 5;
    int hp = t % HP; t /= HP;
    int c = t & 127;
    int b = t >> 7;
    int g = c >> 3;

    const float N = (float)(CPG * HOUT * WOUT);
    float sum   = stats[(b * NGROUPS + g) * 2 + 0];
    float sumsq = stats[(b * NGROUPS + g) * 2 + 1];
    float mean = sum / N;
    float var  = sumsq / N - mean * mean;
    float rstd = rsqrtf(var + EPSV);

    float A  = gnw[c] * rstd * scale[c];
    float B2 = (gnb[c] - mean * gnw[c] * rstd) * scale[c];

    const float* yp = y + (((size_t)b * COUT + c) * HOUT + hp * 2) * WOUT + wp2 * 4;
    float4t r0 = *(const float4t*)yp;                      // row 2hp: 16B-aligned
    float2t r1a = *(const float2t*)(yp + WOUT);            // row 2hp+1: 8B-aligned
    float2t r1b = *(const float2t*)(yp + WOUT + 2);

    float v0 = fmaf(r0.x, A, B2), v1 = fmaf(r0.y, A, B2);
    float v2 = fmaf(r0.z, A, B2), v3 = fmaf(r0.w, A, B2);
    float u0 = fmaf(r1a.x, A, B2), u1 = fmaf(r1a.y, A, B2);
    float u2 = fmaf(r1b.x, A, B2), u3 = fmaf(r1b.y, A, B2);

    float p0 = fmaxf(fmaxf(v0, v1), fmaxf(u0, u1));
    float p1 = fmaxf(fmaxf(v2, v3), fmaxf(u2, u3));
    p0 = fminf(fmaxf(p0, 0.0f), 1.0f);
    p1 = fminf(fmaxf(p1, 0.0f), 1.0f);

    int wp = wp2 * 2;
    size_t o = (((size_t)b * COUT + c) * HP + hp) * WP + wp;
    out[o] = p0;
    if (wp + 1 < WP) out[o + 1] = p1;
}

extern "C" void kernel_launch(void* const* d_in, const int* in_sizes, int n_in,
                              void* d_out, int out_size, void* d_ws, size_t ws_size,
                              hipStream_t stream) {
    const float* x      = (const float*)d_in[0];
    const float* conv_w = (const float*)d_in[1];
    const float* conv_b = (const float*)d_in[2];
    const float* gnw    = (const float*)d_in[3];
    const float* gnb    = (const float*)d_in[4];
    const float* scale  = (const float*)d_in[5];
    float* out = (float*)d_out;

    const size_t y_bytes = (size_t)BATCH * COUT * HOUT * WOUT * sizeof(float);
    float* y     = (float*)d_ws;
    float* stats = (float*)((char*)d_ws + y_bytes);
    _Float16* wT = (_Float16*)((char*)d_ws + y_bytes + 4096);

    wt_kernel<<<(9 * COUT * CIN + 255) / 256, 256, 0, stream>>>(conv_w, wT, stats);

    dim3 grid(HOUT, 2, BATCH);
    conv_mfma_kernel<<<grid, 256, 0, stream>>>(x, wT, conv_b, y, stats);

    const int total = BATCH * COUT * HP * 32;
    norm_pool_kernel<<<total / 256, 256, 0, stream>>>(y, stats, gnw, gnb, scale, out);
}

// Round 5
// 480.967 us; speedup vs baseline: 1.5996x; 1.5996x over previous
//
#include <hip/hip_runtime.h>

typedef _Float16 half8 __attribute__((ext_vector_type(8)));
typedef _Float16 half2t __attribute__((ext_vector_type(2)));
typedef float float4t __attribute__((ext_vector_type(4)));
typedef float float2t __attribute__((ext_vector_type(2)));

#define BATCH 32
#define CIN 64
#define HIN 128
#define WIN 128
#define COUT 128
#define HOUT 126
#define WOUT 126
#define HP 63
#define WP 63
#define NGROUPS 16
#define CPG 8
#define EPSV 1e-5f

#define XS_ROWS 4
#define XS_COLS 66
#define XS_CSTR 72   // cin stride in fp16 elems = 144B: 16B-aligned b128

// wT[pos][cout][cin] fp16, pos = kh*3+kw ; also zeroes stats
__global__ __launch_bounds__(256) void wt_kernel(const float* __restrict__ w,
                                                 _Float16* __restrict__ wT,
                                                 float* __restrict__ stats) {
    int idx = blockIdx.x * 256 + threadIdx.x;
    if (idx < BATCH * NGROUPS * 2) stats[idx] = 0.f;
    if (idx >= 9 * COUT * CIN) return;
    int cin = idx & 63;
    int t = idx >> 6;
    int cout = t & 127;
    int pos = t >> 7;
    wT[idx] = (_Float16)w[(cout * CIN + cin) * 9 + pos];
}

// grid: x = oy-pair (63), y = col-half (2), z = batch (32).
// Block: 512 thr = 8 waves. Wave wv -> couts wv*16..+15, all waves share 64px x 2 output rows.
// A (16 couts x K=576) resident in 72 VGPRs per lane; K-loop has ZERO global loads.
__global__ __launch_bounds__(512, 4) void conv_mfma_kernel(
    const float* __restrict__ x, const _Float16* __restrict__ wT,
    const float* __restrict__ bias, float* __restrict__ y,
    float* __restrict__ stats)
{
    __shared__ __align__(16) _Float16 xs[XS_ROWS * XS_COLS * XS_CSTR];  // 38016 B

    const int tid  = threadIdx.x;
    const int oy0  = blockIdx.x * 2;
    const int half = blockIdx.y;
    const int b    = blockIdx.z;

    const int lane = tid & 63;
    const int wv   = tid >> 6;
    const int m    = lane & 15;
    const int q    = lane >> 4;
    const int c0w  = wv * 16;

    // ---- A fragments: all 18 K-steps resident (72 VGPRs) ----
    half8 a[18];
    {
        const _Float16* ab = wT + (size_t)(c0w + m) * CIN + q * 8;
#pragma unroll
        for (int pos = 0; pos < 9; pos++)
#pragma unroll
            for (int ch = 0; ch < 2; ch++)
                a[pos * 2 + ch] = *(const half8*)(ab + (size_t)pos * COUT * CIN + ch * 32);
    }

    // ---- stage xs[r][col][cin] = fp16(x[b][cin][oy0+r][half*64+col]), r=0..3, col=0..65 ----
    {
        const int cp  = tid & 31;        // cins {2cp, 2cp+1}
        const int seg = tid >> 5;        // 0..15 -> col4 = seg*4 (0..60)
        const int col4 = seg * 4;
        const float* xb = x + ((size_t)b * CIN + 2 * cp) * (HIN * WIN) + half * 64;
#pragma unroll
        for (int r = 0; r < XS_ROWS; r++) {
            const float* p0 = xb + (size_t)(oy0 + r) * WIN + col4;
            float4t va = *(const float4t*)p0;
            float4t vb = *(const float4t*)(p0 + HIN * WIN);
            _Float16* dst = &xs[(r * XS_COLS + col4) * XS_CSTR + 2 * cp];
#pragma unroll
            for (int j = 0; j < 4; j++) {
                half2t hv = { (_Float16)va[j], (_Float16)vb[j] };
                *(half2t*)(dst + j * XS_CSTR) = hv;
            }
        }
        // halo cols 64,65 (zero when half==1 -> x cols 128,129)
        if (tid < 256) {
            int r   = tid >> 6;
            int rem = tid & 63;
            int cpz = rem & 31;
            int col = 64 + (rem >> 5);
            int gx  = half * 64 + col;
            float v0 = 0.f, v1 = 0.f;
            if (gx < WIN) {
                const float* p = x + ((size_t)b * CIN + 2 * cpz) * (HIN * WIN) + (size_t)(oy0 + r) * WIN + gx;
                v0 = p[0];
                v1 = p[HIN * WIN];
            }
            half2t hv = { (_Float16)v0, (_Float16)v1 };
            *(half2t*)&xs[(r * XS_COLS + col) * XS_CSTR + 2 * cpz] = hv;
        }
    }
    __syncthreads();

    float4t acc[2][4];
#pragma unroll
    for (int row = 0; row < 2; row++)
#pragma unroll
        for (int n = 0; n < 4; n++)
            acc[row][n] = (float4t){0.f, 0.f, 0.f, 0.f};

    // ---- K-loop: pure LDS + MFMA. xs row R feeds out-row 0 (kh=R) and out-row 1 (kh=R-1). ----
#pragma unroll
    for (int ch = 0; ch < 2; ch++) {
#pragma unroll
        for (int R = 0; R < XS_ROWS; R++) {
#pragma unroll
            for (int kw = 0; kw < 3; kw++) {
#pragma unroll
                for (int n = 0; n < 4; n++) {
                    half8 bf = *(const half8*)&xs[(R * XS_COLS + n * 16 + m + kw) * XS_CSTR + ch * 32 + q * 8];
                    if (R <= 2)
                        acc[0][n] = __builtin_amdgcn_mfma_f32_16x16x32_f16(a[(R * 3 + kw) * 2 + ch], bf, acc[0][n], 0, 0, 0);
                    if (R >= 1)
                        acc[1][n] = __builtin_amdgcn_mfma_f32_16x16x32_f16(a[((R - 1) * 3 + kw) * 2 + ch], bf, acc[1][n], 0, 0, 0);
                }
            }
        }
    }

    // ---- epilogue: bias, store y (fp32), per-group stats ----
    float bv[4];
#pragma unroll
    for (int reg = 0; reg < 4; reg++) bv[reg] = bias[c0w + q * 4 + reg];

    float sv = 0.f, ssv = 0.f;
#pragma unroll
    for (int row = 0; row < 2; row++) {
#pragma unroll
        for (int n = 0; n < 4; n++) {
            int pix = half * 64 + n * 16 + m;
            bool valid = pix < WOUT;
            float* yp = y + (((size_t)b * COUT + c0w + q * 4) * HOUT + oy0 + row) * WOUT + pix;
#pragma unroll
            for (int reg = 0; reg < 4; reg++) {
                float v = acc[row][n][reg] + bv[reg];
                if (valid) {
                    yp[(size_t)reg * (HOUT * WOUT)] = v;
                    sv += v;
                    ssv += v * v;
                }
            }
        }
    }
    // thread's 4 couts (q*4..q*4+3) are all in group wv*2 + (q>>1):
    // lanes 0..31 -> group wv*2, lanes 32..63 -> wv*2+1
#pragma unroll
    for (int off = 16; off; off >>= 1) {
        sv  += __shfl_down(sv,  off, 32);
        ssv += __shfl_down(ssv, off, 32);
    }
    if ((lane & 31) == 0) {
        int g = wv * 2 + (q >> 1);
        atomicAdd(&stats[(b * NGROUPS + g) * 2 + 0], sv);
        atomicAdd(&stats[(b * NGROUPS + g) * 2 + 1], ssv);
    }
}

// one thread per pooled output (R1 structure: fully-coalesced float2 loads, unit-stride stores)
__global__ __launch_bounds__(256) void norm_pool_kernel(
    const float* __restrict__ y, const float* __restrict__ stats,
    const float* __restrict__ gnw, const float* __restrict__ gnb,
    const float* __restrict__ scale, float* __restrict__ out)
{
    const int total = BATCH * COUT * HP * WP;
    int idx = blockIdx.x * 256 + threadIdx.x;
    if (idx >= total) return;

    int wp = idx % WP;
    int t = idx / WP;
    int hp = t % HP; t /= HP;
    int c = t % COUT;
    int b = t / COUT;
    int g = c / CPG;

    const float N = (float)(CPG * HOUT * WOUT);
    float sum   = stats[(b * NGROUPS + g) * 2 + 0];
    float sumsq = stats[(b * NGROUPS + g) * 2 + 1];
    float mean = sum / N;
    float var  = sumsq / N - mean * mean;
    float rstd = rsqrtf(var + EPSV);

    float A  = gnw[c] * rstd * scale[c];
    float B2 = (gnb[c] - mean * gnw[c] * rstd) * scale[c];

    const float* yp = y + (((size_t)b * COUT + c) * HOUT + hp * 2) * WOUT + wp * 2;
    float2 r0 = *(const float2*)yp;
    float2 r1 = *(const float2*)(yp + WOUT);

    float v0 = fmaf(r0.x, A, B2);
    float v1 = fmaf(r0.y, A, B2);
    float v2 = fmaf(r1.x, A, B2);
    float v3 = fmaf(r1.y, A, B2);
    float mx = fmaxf(fmaxf(v0, v1), fmaxf(v2, v3));
    out[idx] = fminf(fmaxf(mx, 0.0f), 1.0f);
}

extern "C" void kernel_launch(void* const* d_in, const int* in_sizes, int n_in,
                              void* d_out, int out_size, void* d_ws, size_t ws_size,
                              hipStream_t stream) {
    const float* x      = (const float*)d_in[0];
    const float* conv_w = (const float*)d_in[1];
    const float* conv_b = (const float*)d_in[2];
    const float* gnw    = (const float*)d_in[3];
    const float* gnb    = (const float*)d_in[4];
    const float* scale  = (const float*)d_in[5];
    float* out = (float*)d_out;

    const size_t y_bytes = (size_t)BATCH * COUT * HOUT * WOUT * sizeof(float);
    float* y     = (float*)d_ws;
    float* stats = (float*)((char*)d_ws + y_bytes);
    _Float16* wT = (_Float16*)((char*)d_ws + y_bytes + 4096);

    wt_kernel<<<(9 * COUT * CIN + 255) / 256, 256, 0, stream>>>(conv_w, wT, stats);

    dim3 grid(HP, 2, BATCH);   // 63 oy-pairs x 2 col-halves x 32 batch
    conv_mfma_kernel<<<grid, 512, 0, stream>>>(x, wT, conv_b, y, stats);

    const int total = BATCH * COUT * HP * WP;
    norm_pool_kernel<<<(total + 255) / 256, 256, 0, stream>>>(y, stats, gnw, gnb, scale, out);
}